// Round 12
// baseline (436.873 us; speedup 1.0000x reference)
//
#include <hip/hip_runtime.h>

// ---------------------------------------------------------------------------
// ResNet sparse-conv block, round 15: R14 hardened. R12 spconv pair untouched
// (proven floor 134.2us each). prep2 + bn_relu_f32 fused via a MANUAL
// device-scope grid barrier (plain kernel -> graph-capturable; cooperative
// launch is silently dropped by graph capture, R13). Blocks 0..767 own x
// (17 float4 retained in registers across the barrier); 768..821 pack W.
// Co-residency: launch_bounds(256,4) -> 4 blk/CU -> 1024 slots >= 822 grid.
// R15 fix vs R14: phase-C stats reads are AGENT-scope atomic loads (plain
// loads can hit stale-clean zero lines in per-XCD L2 left by the host memset,
// since device-scope atomicAdds bypass those L2s -- G16 non-coherence).
// ---------------------------------------------------------------------------

#define KOFF 27

typedef __bf16 bf16x8 __attribute__((ext_vector_type(8)));
typedef float floatx4 __attribute__((ext_vector_type(4)));

__device__ __forceinline__ unsigned short f2bf(float x) {
    union { float f; unsigned int u; } v; v.f = x;
    unsigned int u = v.u;
    unsigned int r = u + 0x7FFFu + ((u >> 16) & 1u);
    return (unsigned short)(r >> 16);
}
__device__ __forceinline__ float bf2f(unsigned short s) {
    union { float f; unsigned int u; } v; v.u = ((unsigned int)s) << 16; return v.f;
}

// --- fused stats(x)+W-pack | manual grid barrier | BN1+ReLU(x)->bf16 --------
__global__ __launch_bounds__(256, 4) void prep_bn1(
        const float* __restrict__ W1, const float* __restrict__ W2,
        unsigned short* __restrict__ W1f, unsigned short* __restrict__ W2f,
        const float* __restrict__ x, float* __restrict__ stats,
        const float* __restrict__ gamma, const float* __restrict__ beta,
        unsigned short* __restrict__ hbuf, int total4, float invN, int nb) {
    __shared__ float sW[64 * 68];
    __shared__ float s[128];
    int b = blockIdx.x, t = threadIdx.x;
    unsigned* bar = (unsigned*)(stats + 448);
    const int S = 768 * 256;

    // ---- phase A ----
    float4 v[17];
    float a0 = 0.f, a1 = 0.f, a2 = 0.f, a3 = 0.f;
    float b0 = 0.f, b1 = 0.f, b2 = 0.f, b3 = 0.f;
    int c0 = (t << 2) & 63;     // channel of comp 0: 4*tid mod 64 = 4t mod 64
    if (b < 768) {
        if (t < 128) s[t] = 0.f;
        __syncthreads();
        int tid = b * 256 + t;
        #pragma unroll
        for (int j = 0; j < 17; ++j) {
            int i = tid + j * S;
            if (i < total4) {
                v[j] = ((const float4*)x)[i];
                a0 += v[j].x; b0 += v[j].x * v[j].x;
                a1 += v[j].y; b1 += v[j].y * v[j].y;
                a2 += v[j].z; b2 += v[j].z * v[j].z;
                a3 += v[j].w; b3 += v[j].w * v[j].w;
            }
        }
        atomicAdd(&s[c0],     a0); atomicAdd(&s[c0 + 1],     a1);
        atomicAdd(&s[c0 + 2], a2); atomicAdd(&s[c0 + 3],     a3);
        atomicAdd(&s[64 + c0],     b0); atomicAdd(&s[64 + c0 + 1], b1);
        atomicAdd(&s[64 + c0 + 2], b2); atomicAdd(&s[64 + c0 + 3], b3);
        __syncthreads();
        if (t < 128) atomicAdd(&stats[t], s[t]);   // device-scope atomic
    } else {
        int wb = b - 768;
        int k = wb % 27;
        const float* src = (wb < 27 ? W1 : W2) + k * 4096;
        unsigned short* dst = (wb < 27 ? W1f : W2f) + (size_t)k * 4096;
        #pragma unroll
        for (int ii = 0; ii < 4; ++ii) {
            int i4 = t + ii * 256;
            float4 w = ((const float4*)src)[i4];
            int f = i4 * 4, r = f >> 6, c = f & 63;
            sW[r * 68 + c]     = w.x;
            sW[r * 68 + c + 1] = w.y;
            sW[r * 68 + c + 2] = w.z;
            sW[r * 68 + c + 3] = w.w;
        }
        __syncthreads();
        int fi = (t >> 5) & 7, ct = fi >> 1, ks = fi & 1;
        unsigned short o[16];
        #pragma unroll
        for (int d = 0; d < 2; ++d) {
            int lane2 = (t * 2 + d) & 63, q = lane2 >> 4, l15 = lane2 & 15;
            #pragma unroll
            for (int j = 0; j < 8; ++j) {
                int cin = ks * 32 + q * 8 + j, cout = ct * 16 + l15;
                o[d * 8 + j] = f2bf(sW[cin * 68 + cout]);
            }
        }
        ((uint4*)(dst + t * 16))[0] = *(const uint4*)(o);
        ((uint4*)(dst + t * 16))[1] = *(const uint4*)(o + 8);
    }

    // ---- manual grid barrier (one-shot; bar zeroed by host memset) --------
    __syncthreads();
    if (t == 0) {
        __hip_atomic_fetch_add(bar, 1u, __ATOMIC_ACQ_REL, __HIP_MEMORY_SCOPE_AGENT);
        while (__hip_atomic_load(bar, __ATOMIC_ACQUIRE, __HIP_MEMORY_SCOPE_AGENT)
               < (unsigned)nb)
            __builtin_amdgcn_s_sleep(32);
    }
    __syncthreads();
    if (b >= 768) return;

    // ---- phase C: BN1 coefficients + transform retained x -> bf16 ---------
    // stats read via AGENT-scope atomic loads (coherence point), not plain
    // loads: local XCD L2 may hold a stale-clean zero line from the memset.
    if (t < 64) {
        float s1 = __hip_atomic_load(&stats[t],      __ATOMIC_RELAXED, __HIP_MEMORY_SCOPE_AGENT);
        float s2 = __hip_atomic_load(&stats[64 + t], __ATOMIC_RELAXED, __HIP_MEMORY_SCOPE_AGENT);
        float mu  = s1 * invN;
        float var = fmaxf(s2 * invN - mu * mu, 0.f);
        float a   = gamma[t] * rsqrtf(var + 1e-5f);
        s[t] = a; s[64 + t] = beta[t] - mu * a;
    }
    __syncthreads();
    float ca0 = s[c0],      ca1 = s[c0 + 1],      ca2 = s[c0 + 2],      ca3 = s[c0 + 3];
    float cb0 = s[64 + c0], cb1 = s[64 + c0 + 1], cb2 = s[64 + c0 + 2], cb3 = s[64 + c0 + 3];
    int tid = b * 256 + t;
    #pragma unroll
    for (int j = 0; j < 17; ++j) {
        int i = tid + j * S;
        if (i < total4) {
            ushort4 o;
            o.x = f2bf(fmaxf(ca0 * v[j].x + cb0, 0.f));
            o.y = f2bf(fmaxf(ca1 * v[j].y + cb1, 0.f));
            o.z = f2bf(fmaxf(ca2 * v[j].z + cb2, 0.f));
            o.w = f2bf(fmaxf(ca3 * v[j].w + cb3, 0.f));
            ((ushort4*)hbuf)[i] = o;
        }
    }
}

// --- BN + ReLU + bf16 cast, bf16 input --------------------------------------
__global__ void bn_relu_b16(const unsigned short* __restrict__ in, const float* __restrict__ sums,
                            const float* __restrict__ gamma, const float* __restrict__ beta,
                            unsigned short* __restrict__ out, int total8, float invN) {
    __shared__ float sab[128];
    int t = threadIdx.x;
    if (t < 64) {
        float mu  = sums[t] * invN;
        float var = fmaxf(sums[64 + t] * invN - mu * mu, 0.f);
        float a   = gamma[t] * rsqrtf(var + 1e-5f);
        sab[t] = a; sab[64 + t] = beta[t] - mu * a;
    }
    __syncthreads();
    int i = blockIdx.x * blockDim.x + t;
    int stride = gridDim.x * blockDim.x;
    for (; i < total8; i += stride) {
        uint4 v = ((const uint4*)in)[i];
        int c0 = (i << 3) & 63;
        unsigned int w[4] = {v.x, v.y, v.z, v.w};
        unsigned int o[4];
        #pragma unroll
        for (int p = 0; p < 4; ++p) {
            float f0 = bf2f((unsigned short)(w[p] & 0xffff));
            float f1 = bf2f((unsigned short)(w[p] >> 16));
            int c = c0 + p * 2;
            unsigned short r0 = f2bf(fmaxf(sab[c]     * f0 + sab[64 + c],     0.f));
            unsigned short r1 = f2bf(fmaxf(sab[c + 1] * f1 + sab[64 + c + 1], 0.f));
            o[p] = (unsigned int)r0 | ((unsigned int)r1 << 16);
        }
        ((uint4*)out)[i] = make_uint4(o[0], o[1], o[2], o[3]);
    }
}

#define MFMA(a, b, c) __builtin_amdgcn_mfma_f32_16x16x32_bf16(a, b, c, 0, 0, 0)
// lgkmcnt(0), vmcnt=no-wait(63), expcnt=no-wait(7)
#define WAIT_LGKM0() __builtin_amdgcn_s_waitcnt(0xC07F)

// --- LDS-shared-B gather->register MFMA sparse conv (R6 schedule) -----------
__global__ __launch_bounds__(256, 4) void spconv(
        const unsigned short* __restrict__ h,     // [N,64] bf16
        const int* __restrict__ idx,              // [N,27]
        const unsigned short* __restrict__ Wf,    // packed frags [27][8][64][8]
        unsigned short* __restrict__ outb,        // conv1 out (bf16) or null
        float* __restrict__ outf,                 // conv2 out (fp32) or null
        const float* __restrict__ resid,          // conv2 residual or null
        float* __restrict__ stats,                // conv1 fused stats or null
        int N) {
    __shared__ float4 arena[1088];                // 17408 B: sB[2][8KB] | sE 64x68 f32
    __shared__ float sred[128];
    unsigned short* sBb = (unsigned short*)arena; // sB[buf] = sBb + buf*4096
    float* sE = (float*)arena;

    int t = threadIdx.x, lane = t & 63, wid = t >> 6;
    int q = lane >> 4, l15 = lane & 15;
    int base = blockIdx.x * 128;
    if (t < 128) sred[t] = 0.f;

    int r0 = base + wid * 32 + l15;
    int r1 = r0 + 16;
    const int* ip0 = idx + (size_t)min(r0, N - 1) * KOFF;
    const int* ip1 = idx + (size_t)min(r1, N - 1) * KOFF;
    int qo = q * 8;

    floatx4 acc[2][4];
    #pragma unroll
    for (int a_ = 0; a_ < 2; ++a_)
        #pragma unroll
        for (int b_ = 0; b_ < 4; ++b_)
            acc[a_][b_] = floatx4{0.f, 0.f, 0.f, 0.f};

    // ---- prologue: A(0), A(1) gathers; B(0) staged+written; B(1) staged ----
    bf16x8 A0[4], A1[4], A2[4];
    {
        int g0 = ip0[0], g1 = ip1[0];
        const unsigned short* p0 = h + ((size_t)g0 << 6) + qo;
        const unsigned short* p1 = h + ((size_t)g1 << 6) + qo;
        A0[0] = *(const bf16x8*)p0; A0[1] = *(const bf16x8*)(p0 + 32);
        A0[2] = *(const bf16x8*)p1; A0[3] = *(const bf16x8*)(p1 + 32);
        g0 = ip0[1]; g1 = ip1[1];
        p0 = h + ((size_t)g0 << 6) + qo;
        p1 = h + ((size_t)g1 << 6) + qo;
        A1[0] = *(const bf16x8*)p0; A1[1] = *(const bf16x8*)(p0 + 32);
        A1[2] = *(const bf16x8*)p1; A1[3] = *(const bf16x8*)(p1 + 32);
    }
    int gc0 = ip0[2], gc1 = ip1[2];

    const uint4* Wf4 = (const uint4*)Wf;          // 8 shorts per uint4
    int so = wid * 64 + lane;                     // lane-contiguous slot
    uint4 bs0 = Wf4[so], bs1 = Wf4[256 + so];     // B(0)
    ((uint4*)sBb)[so] = bs0; ((uint4*)sBb)[256 + so] = bs1;
    bs0 = Wf4[512 + so]; bs1 = Wf4[512 + 256 + so];   // B(1) staged in regs

#define COMPUTE(ACUR, CB) {                                                    \
    const bf16x8* bp = (const bf16x8*)(sBb + (CB) * 4096);                     \
    bf16x8 f0 = bp[lane], f1 = bp[64 + lane], f2 = bp[128 + lane], f3 = bp[192 + lane]; \
    acc[0][0] = MFMA(ACUR[0], f0, acc[0][0]); acc[0][0] = MFMA(ACUR[1], f1, acc[0][0]); \
    acc[0][1] = MFMA(ACUR[0], f2, acc[0][1]); acc[0][1] = MFMA(ACUR[1], f3, acc[0][1]); \
    acc[1][0] = MFMA(ACUR[2], f0, acc[1][0]); acc[1][0] = MFMA(ACUR[3], f1, acc[1][0]); \
    acc[1][1] = MFMA(ACUR[2], f2, acc[1][1]); acc[1][1] = MFMA(ACUR[3], f3, acc[1][1]); \
    f0 = bp[256 + lane]; f1 = bp[320 + lane]; f2 = bp[384 + lane]; f3 = bp[448 + lane]; \
    acc[0][2] = MFMA(ACUR[0], f0, acc[0][2]); acc[0][2] = MFMA(ACUR[1], f1, acc[0][2]); \
    acc[0][3] = MFMA(ACUR[0], f2, acc[0][3]); acc[0][3] = MFMA(ACUR[1], f3, acc[0][3]); \
    acc[1][2] = MFMA(ACUR[2], f0, acc[1][2]); acc[1][2] = MFMA(ACUR[3], f1, acc[1][2]); \
    acc[1][3] = MFMA(ACUR[2], f2, acc[1][3]); acc[1][3] = MFMA(ACUR[3], f3, acc[1][3]); \
}

#define BODY_FULL(ACUR, ALD, KRT, CB, NB) {                                    \
    WAIT_LGKM0();                                                              \
    __builtin_amdgcn_s_barrier();                                              \
    ((uint4*)sBb)[(NB) * 512 + so] = bs0;                                      \
    ((uint4*)sBb)[(NB) * 512 + 256 + so] = bs1;                                \
    bs0 = Wf4[((KRT) + 2) * 512 + so]; bs1 = Wf4[((KRT) + 2) * 512 + 256 + so];\
    {                                                                          \
        const unsigned short* p0 = h + ((size_t)gc0 << 6) + qo;                \
        const unsigned short* p1 = h + ((size_t)gc1 << 6) + qo;                \
        ALD[0] = *(const bf16x8*)p0; ALD[1] = *(const bf16x8*)(p0 + 32);       \
        ALD[2] = *(const bf16x8*)p1; ALD[3] = *(const bf16x8*)(p1 + 32);       \
    }                                                                          \
    gc0 = ip0[(KRT) + 3]; gc1 = ip1[(KRT) + 3];                                \
    COMPUTE(ACUR, CB)                                                          \
}

    #pragma unroll 1
    for (int kk = 0; kk < 24; kk += 6) {
        BODY_FULL(A0, A2, kk + 0, 0, 1)
        BODY_FULL(A1, A0, kk + 1, 1, 0)
        BODY_FULL(A2, A1, kk + 2, 0, 1)
        BODY_FULL(A0, A2, kk + 3, 1, 0)
        BODY_FULL(A1, A0, kk + 4, 0, 1)
        BODY_FULL(A2, A1, kk + 5, 1, 0)
    }
    // k = 24: write B(25), stage B(26), gather A(26)
    {
        WAIT_LGKM0();
        __builtin_amdgcn_s_barrier();
        ((uint4*)sBb)[512 + so] = bs0; ((uint4*)sBb)[512 + 256 + so] = bs1;
        bs0 = Wf4[26 * 512 + so]; bs1 = Wf4[26 * 512 + 256 + so];
        {
            const unsigned short* p0 = h + ((size_t)gc0 << 6) + qo;
            const unsigned short* p1 = h + ((size_t)gc1 << 6) + qo;
            A2[0] = *(const bf16x8*)p0; A2[1] = *(const bf16x8*)(p0 + 32);
            A2[2] = *(const bf16x8*)p1; A2[3] = *(const bf16x8*)(p1 + 32);
        }
        COMPUTE(A0, 0)
    }
    // k = 25: write B(26)
    {
        WAIT_LGKM0();
        __builtin_amdgcn_s_barrier();
        ((uint4*)sBb)[so] = bs0; ((uint4*)sBb)[256 + so] = bs1;
        COMPUTE(A1, 1)
    }
    // k = 26
    {
        WAIT_LGKM0();
        __builtin_amdgcn_s_barrier();
        COMPUTE(A2, 0)
    }
#undef BODY_FULL
#undef COMPUTE

    // fused per-channel stats of conv1 output (tail rows masked)
    if (stats) {
        #pragma unroll
        for (int ct = 0; ct < 4; ++ct) {
            float s1 = 0.f, s2 = 0.f;
            #pragma unroll
            for (int rt = 0; rt < 2; ++rt)
                #pragma unroll
                for (int r = 0; r < 4; ++r) {
                    int rowc = base + wid * 32 + rt * 16 + q * 4 + r;
                    float vv = (rowc < N) ? acc[rt][ct][r] : 0.f;
                    s1 += vv; s2 += vv * vv;
                }
            s1 += __shfl_xor(s1, 16); s2 += __shfl_xor(s2, 16);
            s1 += __shfl_xor(s1, 32); s2 += __shfl_xor(s2, 32);
            if (q == 0) {
                atomicAdd(&sred[ct * 16 + l15], s1);
                atomicAdd(&sred[64 + ct * 16 + l15], s2);
            }
        }
    }

    __syncthreads();   // all sB reads done before sE (alias) is written

    // epilogue: two 64-row halves through the arena (aliases sB)
    #pragma unroll
    for (int hf = 0; hf < 2; ++hf) {
        if ((wid >> 1) == hf) {
            int lrow0 = (wid & 1) * 32;
            #pragma unroll
            for (int rt = 0; rt < 2; ++rt)
                #pragma unroll
                for (int ct = 0; ct < 4; ++ct)
                    #pragma unroll
                    for (int r = 0; r < 4; ++r)
                        sE[(lrow0 + rt * 16 + q * 4 + r) * 68 + ct * 16 + l15] = acc[rt][ct][r];
        }
        __syncthreads();
        if (hf == 0 && stats && t < 64) {
            atomicAdd(&stats[t], sred[t]);
            atomicAdd(&stats[64 + t], sred[64 + t]);
        }
        int rr = t >> 2, cc = t & 3;
        int grow = base + hf * 64 + rr;
        if (grow < N) {
            const float* sp = sE + rr * 68 + cc * 16;
            if (outb) {
                unsigned short o[16];
                #pragma unroll
                for (int j = 0; j < 16; ++j) o[j] = f2bf(sp[j]);
                unsigned short* op = outb + ((size_t)grow << 6) + cc * 16;
                ((uint4*)op)[0] = *(const uint4*)(o);
                ((uint4*)op)[1] = *(const uint4*)(o + 8);
            } else {
                const float* rp = resid + ((size_t)grow << 6) + cc * 16;
                float* op = outf + ((size_t)grow << 6) + cc * 16;
                #pragma unroll
                for (int j = 0; j < 4; ++j) {
                    float4 v = *(const float4*)(sp + j * 4);
                    float4 rv = *(const float4*)(rp + j * 4);
                    v.x += rv.x; v.y += rv.y; v.z += rv.z; v.w += rv.w;
                    *(float4*)(op + j * 4) = v;
                }
            }
        }
        if (hf == 0) __syncthreads();
    }
}

// ---------------------------------------------------------------------------
extern "C" void kernel_launch(void* const* d_in, const int* in_sizes, int n_in,
                              void* d_out, int out_size, void* d_ws, size_t ws_size,
                              hipStream_t stream) {
    const float* x      = (const float*)d_in[0];
    const int*   nbr    = (const int*)  d_in[1];
    const float* W1     = (const float*)d_in[2];
    const float* gamma1 = (const float*)d_in[3];
    const float* beta1  = (const float*)d_in[4];
    const float* W2     = (const float*)d_in[5];
    const float* gamma2 = (const float*)d_in[6];
    const float* beta2  = (const float*)d_in[7];
    float* out = (float*)d_out;

    int N = in_sizes[0] / 64;
    float invN = 1.0f / (float)N;

    char* ws = (char*)d_ws;
    float*          stats = (float*)ws;                           // 512 floats (barrier @448)
    unsigned short* W1f   = (unsigned short*)(ws + 4096);         // 110592 bf16
    unsigned short* W2f   = W1f + 110592;
    unsigned short* hbuf  = W2f + 110592;                         // [N,64] bf16
    unsigned short* out1b = hbuf + (size_t)N * 64;                // [N,64] bf16

    int nb = (N + 127) / 128;
    int total4 = N * 16;
    int pgrid = 822;                                              // 768 x-duty + 54 W-duty

    hipMemsetAsync(stats, 0, 2048, stream);
    prep_bn1<<<pgrid, 256, 0, stream>>>(W1, W2, W1f, W2f, x, stats,
                                        gamma1, beta1, hbuf, total4, invN, pgrid);
    spconv<<<nb, 256, 0, stream>>>(hbuf, nbr, W1f, out1b, nullptr, nullptr, stats + 256, N);
    bn_relu_b16<<<768, 256, 0, stream>>>(out1b, stats + 256, gamma2, beta2, hbuf, N * 8, invN);
    spconv<<<nb, 256, 0, stream>>>(hbuf, nbr, W2f, nullptr, out, x, nullptr, N);
}

// Round 13
// 403.528 us; speedup vs baseline: 1.0826x; 1.0826x over previous
//
#include <hip/hip_runtime.h>

// ---------------------------------------------------------------------------
// ResNet sparse-conv block, FINAL (= R12, session optimum, 405.5us):
// - spconv (R6 schedule): 3-deep A-gather reg ring, ds_write B staging,
//   lgkm-only explicit waits, arena-aliased epilogue. 134.3us each —
//   access-pattern roofline (375MB FETCH floor confirmed by 3 L2 schemes).
// - prep2 with float4 stats pass (twice-confirmed -20us vs scalar).
// - separate bn_relu passes (all fusions regressed: spill x2, barrier +31us,
//   cooperative launch not graph-capturable).
// ---------------------------------------------------------------------------

#define KOFF 27

typedef __bf16 bf16x8 __attribute__((ext_vector_type(8)));
typedef float floatx4 __attribute__((ext_vector_type(4)));

__device__ __forceinline__ unsigned short f2bf(float x) {
    union { float f; unsigned int u; } v; v.f = x;
    unsigned int u = v.u;
    unsigned int r = u + 0x7FFFu + ((u >> 16) & 1u);
    return (unsigned short)(r >> 16);
}
__device__ __forceinline__ float bf2f(unsigned short s) {
    union { float f; unsigned int u; } v; v.u = ((unsigned int)s) << 16; return v.f;
}

// --- prep: blocks 0..53 pack W (coalesced, LDS transpose); rest: x stats ----
// frag element j of (ct,ks) for lane (q,l15) = W[k][cin=ks*32+q*8+j][cout=ct*16+l15]
__global__ void prep2(const float* __restrict__ W1, const float* __restrict__ W2,
                      unsigned short* __restrict__ W1f, unsigned short* __restrict__ W2f,
                      const float* __restrict__ x, float* __restrict__ stats,
                      int total4) {
    int b = blockIdx.x, t = threadIdx.x;
    if (b < 54) {
        __shared__ float sW[64 * 68];
        int k = b % 27;
        const float* src = (b < 27 ? W1 : W2) + k * 4096;
        unsigned short* dst = (b < 27 ? W1f : W2f) + (size_t)k * 4096;
        #pragma unroll
        for (int i = 0; i < 4; ++i) {
            int i4 = t + i * 256;
            float4 v = ((const float4*)src)[i4];
            int f = i4 * 4, r = f >> 6, c = f & 63;
            sW[r * 68 + c]     = v.x;
            sW[r * 68 + c + 1] = v.y;
            sW[r * 68 + c + 2] = v.z;
            sW[r * 68 + c + 3] = v.w;
        }
        __syncthreads();
        int fi = (t >> 5) & 7, ct = fi >> 1, ks = fi & 1;
        unsigned short o[16];
        #pragma unroll
        for (int d = 0; d < 2; ++d) {
            int lane2 = (t * 2 + d) & 63, q = lane2 >> 4, l15 = lane2 & 15;
            #pragma unroll
            for (int j = 0; j < 8; ++j) {
                int cin = ks * 32 + q * 8 + j, cout = ct * 16 + l15;
                o[d * 8 + j] = f2bf(sW[cin * 68 + cout]);
            }
        }
        ((uint4*)(dst + t * 16))[0] = *(const uint4*)(o);
        ((uint4*)(dst + t * 16))[1] = *(const uint4*)(o + 8);
        return;
    }
    __shared__ float s[128];
    if (t < 128) s[t] = 0.f;
    __syncthreads();
    int i = (b - 54) * 256 + t;
    int stride = (gridDim.x - 54) * 256;
    // float4 loads; channel of component 0 is (4t)&63 (block/grid strides are
    // multiples of 64 channels).
    float a0 = 0.f, a1 = 0.f, a2 = 0.f, a3 = 0.f;
    float b0 = 0.f, b1 = 0.f, b2 = 0.f, b3 = 0.f;
    for (; i < total4; i += stride) {
        float4 v = ((const float4*)x)[i];
        a0 += v.x; b0 += v.x * v.x;
        a1 += v.y; b1 += v.y * v.y;
        a2 += v.z; b2 += v.z * v.z;
        a3 += v.w; b3 += v.w * v.w;
    }
    int c0 = (t << 2) & 63;
    atomicAdd(&s[c0],     a0); atomicAdd(&s[c0 + 1],     a1);
    atomicAdd(&s[c0 + 2], a2); atomicAdd(&s[c0 + 3],     a3);
    atomicAdd(&s[64 + c0],     b0); atomicAdd(&s[64 + c0 + 1], b1);
    atomicAdd(&s[64 + c0 + 2], b2); atomicAdd(&s[64 + c0 + 3], b3);
    __syncthreads();
    if (t < 64) { atomicAdd(&stats[t], s[t]); atomicAdd(&stats[64 + t], s[64 + t]); }
}

// --- BN + ReLU + bf16 cast, fp32 input --------------------------------------
__global__ void bn_relu_f32(const float* __restrict__ in, const float* __restrict__ sums,
                            const float* __restrict__ gamma, const float* __restrict__ beta,
                            unsigned short* __restrict__ out, int total4, float invN) {
    __shared__ float sab[128];
    int t = threadIdx.x;
    if (t < 64) {
        float mu  = sums[t] * invN;
        float var = fmaxf(sums[64 + t] * invN - mu * mu, 0.f);
        float a   = gamma[t] * rsqrtf(var + 1e-5f);
        sab[t] = a; sab[64 + t] = beta[t] - mu * a;
    }
    __syncthreads();
    int i = blockIdx.x * blockDim.x + t;
    int stride = gridDim.x * blockDim.x;
    for (; i < total4; i += stride) {
        float4 v = ((const float4*)in)[i];
        int c0 = (i << 2) & 63;
        ushort4 o;
        o.x = f2bf(fmaxf(sab[c0]     * v.x + sab[64 + c0],     0.f));
        o.y = f2bf(fmaxf(sab[c0 + 1] * v.y + sab[64 + c0 + 1], 0.f));
        o.z = f2bf(fmaxf(sab[c0 + 2] * v.z + sab[64 + c0 + 2], 0.f));
        o.w = f2bf(fmaxf(sab[c0 + 3] * v.w + sab[64 + c0 + 3], 0.f));
        ((ushort4*)out)[i] = o;
    }
}

// --- BN + ReLU + bf16 cast, bf16 input --------------------------------------
__global__ void bn_relu_b16(const unsigned short* __restrict__ in, const float* __restrict__ sums,
                            const float* __restrict__ gamma, const float* __restrict__ beta,
                            unsigned short* __restrict__ out, int total8, float invN) {
    __shared__ float sab[128];
    int t = threadIdx.x;
    if (t < 64) {
        float mu  = sums[t] * invN;
        float var = fmaxf(sums[64 + t] * invN - mu * mu, 0.f);
        float a   = gamma[t] * rsqrtf(var + 1e-5f);
        sab[t] = a; sab[64 + t] = beta[t] - mu * a;
    }
    __syncthreads();
    int i = blockIdx.x * blockDim.x + t;
    int stride = gridDim.x * blockDim.x;
    for (; i < total8; i += stride) {
        uint4 v = ((const uint4*)in)[i];
        int c0 = (i << 3) & 63;
        unsigned int w[4] = {v.x, v.y, v.z, v.w};
        unsigned int o[4];
        #pragma unroll
        for (int p = 0; p < 4; ++p) {
            float f0 = bf2f((unsigned short)(w[p] & 0xffff));
            float f1 = bf2f((unsigned short)(w[p] >> 16));
            int c = c0 + p * 2;
            unsigned short r0 = f2bf(fmaxf(sab[c]     * f0 + sab[64 + c],     0.f));
            unsigned short r1 = f2bf(fmaxf(sab[c + 1] * f1 + sab[64 + c + 1], 0.f));
            o[p] = (unsigned int)r0 | ((unsigned int)r1 << 16);
        }
        ((uint4*)out)[i] = make_uint4(o[0], o[1], o[2], o[3]);
    }
}

#define MFMA(a, b, c) __builtin_amdgcn_mfma_f32_16x16x32_bf16(a, b, c, 0, 0, 0)
// lgkmcnt(0), vmcnt=no-wait(63), expcnt=no-wait(7)
#define WAIT_LGKM0() __builtin_amdgcn_s_waitcnt(0xC07F)

// --- LDS-shared-B gather->register MFMA sparse conv (R6 schedule) -----------
// Block 256 thr (4 waves), 128 output rows; wave owns two 16-row m-tiles.
// Per k: block stages the 8KB B-set once (lane-contiguous uint4 ds_writes,
// conflict-free); A-frags gathered 2 iters ahead into a 3-deep reg buffer.
// Raw s_barrier + lgkmcnt(0) only -> A/B prefetches stay in flight.
// Epilogue transpose buffer ALIASES the B double-buffer (arena) -> ~18KB LDS.
__global__ __launch_bounds__(256, 4) void spconv(
        const unsigned short* __restrict__ h,     // [N,64] bf16
        const int* __restrict__ idx,              // [N,27]
        const unsigned short* __restrict__ Wf,    // packed frags [27][8][64][8]
        unsigned short* __restrict__ outb,        // conv1 out (bf16) or null
        float* __restrict__ outf,                 // conv2 out (fp32) or null
        const float* __restrict__ resid,          // conv2 residual or null
        float* __restrict__ stats,                // conv1 fused stats or null
        int N) {
    __shared__ float4 arena[1088];                // 17408 B: sB[2][8KB] | sE 64x68 f32
    __shared__ float sred[128];
    unsigned short* sBb = (unsigned short*)arena; // sB[buf] = sBb + buf*4096
    float* sE = (float*)arena;

    int t = threadIdx.x, lane = t & 63, wid = t >> 6;
    int q = lane >> 4, l15 = lane & 15;
    int base = blockIdx.x * 128;
    if (t < 128) sred[t] = 0.f;

    int r0 = base + wid * 32 + l15;
    int r1 = r0 + 16;
    const int* ip0 = idx + (size_t)min(r0, N - 1) * KOFF;
    const int* ip1 = idx + (size_t)min(r1, N - 1) * KOFF;
    int qo = q * 8;

    floatx4 acc[2][4];
    #pragma unroll
    for (int a_ = 0; a_ < 2; ++a_)
        #pragma unroll
        for (int b_ = 0; b_ < 4; ++b_)
            acc[a_][b_] = floatx4{0.f, 0.f, 0.f, 0.f};

    // ---- prologue: A(0), A(1) gathers; B(0) staged+written; B(1) staged ----
    bf16x8 A0[4], A1[4], A2[4];
    {
        int g0 = ip0[0], g1 = ip1[0];
        const unsigned short* p0 = h + ((size_t)g0 << 6) + qo;
        const unsigned short* p1 = h + ((size_t)g1 << 6) + qo;
        A0[0] = *(const bf16x8*)p0; A0[1] = *(const bf16x8*)(p0 + 32);
        A0[2] = *(const bf16x8*)p1; A0[3] = *(const bf16x8*)(p1 + 32);
        g0 = ip0[1]; g1 = ip1[1];
        p0 = h + ((size_t)g0 << 6) + qo;
        p1 = h + ((size_t)g1 << 6) + qo;
        A1[0] = *(const bf16x8*)p0; A1[1] = *(const bf16x8*)(p0 + 32);
        A1[2] = *(const bf16x8*)p1; A1[3] = *(const bf16x8*)(p1 + 32);
    }
    int gc0 = ip0[2], gc1 = ip1[2];

    const uint4* Wf4 = (const uint4*)Wf;          // 8 shorts per uint4
    int so = wid * 64 + lane;                     // lane-contiguous slot
    uint4 bs0 = Wf4[so], bs1 = Wf4[256 + so];     // B(0)
    ((uint4*)sBb)[so] = bs0; ((uint4*)sBb)[256 + so] = bs1;
    bs0 = Wf4[512 + so]; bs1 = Wf4[512 + 256 + so];   // B(1) staged in regs

#define COMPUTE(ACUR, CB) {                                                    \
    const bf16x8* bp = (const bf16x8*)(sBb + (CB) * 4096);                     \
    bf16x8 f0 = bp[lane], f1 = bp[64 + lane], f2 = bp[128 + lane], f3 = bp[192 + lane]; \
    acc[0][0] = MFMA(ACUR[0], f0, acc[0][0]); acc[0][0] = MFMA(ACUR[1], f1, acc[0][0]); \
    acc[0][1] = MFMA(ACUR[0], f2, acc[0][1]); acc[0][1] = MFMA(ACUR[1], f3, acc[0][1]); \
    acc[1][0] = MFMA(ACUR[2], f0, acc[1][0]); acc[1][0] = MFMA(ACUR[3], f1, acc[1][0]); \
    acc[1][1] = MFMA(ACUR[2], f2, acc[1][1]); acc[1][1] = MFMA(ACUR[3], f3, acc[1][1]); \
    f0 = bp[256 + lane]; f1 = bp[320 + lane]; f2 = bp[384 + lane]; f3 = bp[448 + lane]; \
    acc[0][2] = MFMA(ACUR[0], f0, acc[0][2]); acc[0][2] = MFMA(ACUR[1], f1, acc[0][2]); \
    acc[0][3] = MFMA(ACUR[0], f2, acc[0][3]); acc[0][3] = MFMA(ACUR[1], f3, acc[0][3]); \
    acc[1][2] = MFMA(ACUR[2], f0, acc[1][2]); acc[1][2] = MFMA(ACUR[3], f1, acc[1][2]); \
    acc[1][3] = MFMA(ACUR[2], f2, acc[1][3]); acc[1][3] = MFMA(ACUR[3], f3, acc[1][3]); \
}

#define BODY_FULL(ACUR, ALD, KRT, CB, NB) {                                    \
    WAIT_LGKM0();                                                              \
    __builtin_amdgcn_s_barrier();                                              \
    ((uint4*)sBb)[(NB) * 512 + so] = bs0;                                      \
    ((uint4*)sBb)[(NB) * 512 + 256 + so] = bs1;                                \
    bs0 = Wf4[((KRT) + 2) * 512 + so]; bs1 = Wf4[((KRT) + 2) * 512 + 256 + so];\
    {                                                                          \
        const unsigned short* p0 = h + ((size_t)gc0 << 6) + qo;                \
        const unsigned short* p1 = h + ((size_t)gc1 << 6) + qo;                \
        ALD[0] = *(const bf16x8*)p0; ALD[1] = *(const bf16x8*)(p0 + 32);       \
        ALD[2] = *(const bf16x8*)p1; ALD[3] = *(const bf16x8*)(p1 + 32);       \
    }                                                                          \
    gc0 = ip0[(KRT) + 3]; gc1 = ip1[(KRT) + 3];                                \
    COMPUTE(ACUR, CB)                                                          \
}

    #pragma unroll 1
    for (int kk = 0; kk < 24; kk += 6) {
        BODY_FULL(A0, A2, kk + 0, 0, 1)
        BODY_FULL(A1, A0, kk + 1, 1, 0)
        BODY_FULL(A2, A1, kk + 2, 0, 1)
        BODY_FULL(A0, A2, kk + 3, 1, 0)
        BODY_FULL(A1, A0, kk + 4, 0, 1)
        BODY_FULL(A2, A1, kk + 5, 1, 0)
    }
    // k = 24: write B(25), stage B(26), gather A(26)
    {
        WAIT_LGKM0();
        __builtin_amdgcn_s_barrier();
        ((uint4*)sBb)[512 + so] = bs0; ((uint4*)sBb)[512 + 256 + so] = bs1;
        bs0 = Wf4[26 * 512 + so]; bs1 = Wf4[26 * 512 + 256 + so];
        {
            const unsigned short* p0 = h + ((size_t)gc0 << 6) + qo;
            const unsigned short* p1 = h + ((size_t)gc1 << 6) + qo;
            A2[0] = *(const bf16x8*)p0; A2[1] = *(const bf16x8*)(p0 + 32);
            A2[2] = *(const bf16x8*)p1; A2[3] = *(const bf16x8*)(p1 + 32);
        }
        COMPUTE(A0, 0)
    }
    // k = 25: write B(26)
    {
        WAIT_LGKM0();
        __builtin_amdgcn_s_barrier();
        ((uint4*)sBb)[so] = bs0; ((uint4*)sBb)[256 + so] = bs1;
        COMPUTE(A1, 1)
    }
    // k = 26
    {
        WAIT_LGKM0();
        __builtin_amdgcn_s_barrier();
        COMPUTE(A2, 0)
    }
#undef BODY_FULL
#undef COMPUTE

    // fused per-channel stats of conv1 output (tail rows masked)
    if (stats) {
        #pragma unroll
        for (int ct = 0; ct < 4; ++ct) {
            float s1 = 0.f, s2 = 0.f;
            #pragma unroll
            for (int rt = 0; rt < 2; ++rt)
                #pragma unroll
                for (int r = 0; r < 4; ++r) {
                    int rowc = base + wid * 32 + rt * 16 + q * 4 + r;
                    float vv = (rowc < N) ? acc[rt][ct][r] : 0.f;
                    s1 += vv; s2 += vv * vv;
                }
            s1 += __shfl_xor(s1, 16); s2 += __shfl_xor(s2, 16);
            s1 += __shfl_xor(s1, 32); s2 += __shfl_xor(s2, 32);
            if (q == 0) {
                atomicAdd(&sred[ct * 16 + l15], s1);
                atomicAdd(&sred[64 + ct * 16 + l15], s2);
            }
        }
    }

    __syncthreads();   // all sB reads done before sE (alias) is written

    // epilogue: two 64-row halves through the arena (aliases sB)
    #pragma unroll
    for (int hf = 0; hf < 2; ++hf) {
        if ((wid >> 1) == hf) {
            int lrow0 = (wid & 1) * 32;
            #pragma unroll
            for (int rt = 0; rt < 2; ++rt)
                #pragma unroll
                for (int ct = 0; ct < 4; ++ct)
                    #pragma unroll
                    for (int r = 0; r < 4; ++r)
                        sE[(lrow0 + rt * 16 + q * 4 + r) * 68 + ct * 16 + l15] = acc[rt][ct][r];
        }
        __syncthreads();
        if (hf == 0 && stats && t < 64) {
            atomicAdd(&stats[t], sred[t]);
            atomicAdd(&stats[64 + t], sred[64 + t]);
        }
        int rr = t >> 2, cc = t & 3;
        int grow = base + hf * 64 + rr;
        if (grow < N) {
            const float* sp = sE + rr * 68 + cc * 16;
            if (outb) {
                unsigned short o[16];
                #pragma unroll
                for (int j = 0; j < 16; ++j) o[j] = f2bf(sp[j]);
                unsigned short* op = outb + ((size_t)grow << 6) + cc * 16;
                ((uint4*)op)[0] = *(const uint4*)(o);
                ((uint4*)op)[1] = *(const uint4*)(o + 8);
            } else {
                const float* rp = resid + ((size_t)grow << 6) + cc * 16;
                float* op = outf + ((size_t)grow << 6) + cc * 16;
                #pragma unroll
                for (int j = 0; j < 4; ++j) {
                    float4 v = *(const float4*)(sp + j * 4);
                    float4 rv = *(const float4*)(rp + j * 4);
                    v.x += rv.x; v.y += rv.y; v.z += rv.z; v.w += rv.w;
                    *(float4*)(op + j * 4) = v;
                }
            }
        }
        if (hf == 0) __syncthreads();
    }
}

// ---------------------------------------------------------------------------
extern "C" void kernel_launch(void* const* d_in, const int* in_sizes, int n_in,
                              void* d_out, int out_size, void* d_ws, size_t ws_size,
                              hipStream_t stream) {
    const float* x      = (const float*)d_in[0];
    const int*   nbr    = (const int*)  d_in[1];
    const float* W1     = (const float*)d_in[2];
    const float* gamma1 = (const float*)d_in[3];
    const float* beta1  = (const float*)d_in[4];
    const float* W2     = (const float*)d_in[5];
    const float* gamma2 = (const float*)d_in[6];
    const float* beta2  = (const float*)d_in[7];
    float* out = (float*)d_out;

    int N = in_sizes[0] / 64;
    float invN = 1.0f / (float)N;

    char* ws = (char*)d_ws;
    float*          stats = (float*)ws;                           // 512 floats
    unsigned short* W1f   = (unsigned short*)(ws + 4096);         // 110592 bf16
    unsigned short* W2f   = W1f + 110592;
    unsigned short* hbuf  = W2f + 110592;                         // [N,64] bf16
    unsigned short* out1b = hbuf + (size_t)N * 64;                // [N,64] bf16

    int nb = (N + 127) / 128;

    hipMemsetAsync(stats, 0, 2048, stream);
    prep2<<<54 + 512, 256, 0, stream>>>(W1, W2, W1f, W2f, x, stats, N * 16);
    bn_relu_f32<<<768, 256, 0, stream>>>(x, stats, gamma1, beta1, hbuf, N * 16, invN);
    spconv<<<nb, 256, 0, stream>>>(hbuf, nbr, W1f, out1b, nullptr, nullptr, stats + 256, N);
    bn_relu_b16<<<768, 256, 0, stream>>>(out1b, stats + 256, gamma2, beta2, hbuf, N * 8, invN);
    spconv<<<nb, 256, 0, stream>>>(hbuf, nbr, W2f, nullptr, out, x, nullptr, N);
}